// Round 2
// baseline (343.038 us; speedup 1.0000x reference)
//
#include <hip/hip_runtime.h>
#include <cmath>

#define B_ 32
#define N_ 4096
#define IN_DIM 125
#define ADIM 128
#define KDIM 64
#define DMODEL 1024
#define HID 64
#define KEFF 256
#define EPS_ 1e-6f

// ---------- k0: convert MLP weights to f64 (once per launch) ----------
__global__ __launch_bounds__(256) void k0_cvt(
    const float* __restrict__ W1, const float* __restrict__ b1,
    const float* __restrict__ W2, const float* __restrict__ b2,
    double* __restrict__ W1D, double* __restrict__ b1D,
    double* __restrict__ W2D, double* __restrict__ b2D)
{
  int t = blockIdx.x * 256 + threadIdx.x;
  if (t < IN_DIM * HID) W1D[t] = (double)W1[t];
  if (t < HID) { b1D[t] = (double)b1[t]; W2D[t] = (double)W2[t]; }
  if (t == 0) b2D[0] = (double)b2[0];
}

// ---------- k1: saliency MLP in fp64, SMEM-free inner loop ----------
// Round-1 diagnosis: the old loop mixed ds_read (x) with s_load (W).
// SMEM completes out-of-order wrt lgkmcnt -> compiler must drain
// lgkmcnt(0) every iteration -> W prefetch dead, K$-miss latency exposed
// (VALUBusy pinned ~52% at BOTH 2.9 and 5.5 waves/SIMD).
// New structure: lane = hidden neuron j (64 lanes = 64 j), wave owns 8
// points. W[d][lane] is a per-lane coalesced VMEM load (vmcnt, manually
// prefetched 4 rows deep, L2-resident). x is staged TRANSPOSED+PRE-
// CONVERTED to f64 in LDS -> inner loop is 8 uniform broadcast f64 reads
// + 8 v_fma_f64 per row, zero cvt, DS-only lgkmcnt. Floor 26.7us.
#define K1_PTS 64
__global__ __launch_bounds__(512) void k1_saliency(
    const float* __restrict__ x, const double* __restrict__ W1D,
    const double* __restrict__ b1D, const double* __restrict__ W2D,
    const double* __restrict__ b2D, double* __restrict__ salD,
    float* __restrict__ salF)
{
  __shared__ double xt[K1_PTS * IN_DIM];   // [125][64] f64 = 64000 B
  __shared__ double red[K1_PTS];           // 512 B  (total 64512 <= 64K)
  int tid = threadIdx.x;
  int p0 = blockIdx.x * K1_PTS;

  { // stage x transposed to f64: xt[d*64+p] = x[p0+p][d]
    // consecutive lanes -> consecutive p -> conflict-free ds_write_b64;
    // global reads strided (500B) but tile is contiguous -> L1 absorbs.
    const float* xg = x + (size_t)p0 * IN_DIM;
    for (int i = tid; i < K1_PTS * IN_DIM; i += 512) {
      int p = i & 63, d = i >> 6;
      xt[i] = (double)xg[p * IN_DIM + d];
    }
  }
  __syncthreads();

  int wv = __builtin_amdgcn_readfirstlane(tid >> 6);
  int lane = tid & 63;

  double acc[8];
  double binit = b1D[lane];
  #pragma unroll
  for (int q = 0; q < 8; ++q) acc[q] = binit;

  // per-lane W column (j = lane), rows ascending, 4-deep register prefetch
  const double* wbase = W1D + lane;
  double wr0 = wbase[0], wr1 = wbase[64], wr2 = wbase[128], wr3 = wbase[192];
  const double* wp = wbase + 256;
  const double* xr = xt + (wv << 3);

  #pragma unroll 1
  for (int d = 0; d < 124; d += 4) {
    // prefetch rows d+4..d+7 (last iter over-reads into b1D region of the
    // same workspace allocation: valid memory, values never used)
    double wn0 = wp[0], wn1 = wp[64], wn2 = wp[128], wn3 = wp[192];
    wp += 256;
    #pragma unroll
    for (int q = 0; q < 8; ++q) acc[q] = fma(xr[q],       wr0, acc[q]);
    #pragma unroll
    for (int q = 0; q < 8; ++q) acc[q] = fma(xr[64 + q],  wr1, acc[q]);
    #pragma unroll
    for (int q = 0; q < 8; ++q) acc[q] = fma(xr[128 + q], wr2, acc[q]);
    #pragma unroll
    for (int q = 0; q < 8; ++q) acc[q] = fma(xr[192 + q], wr3, acc[q]);
    xr += 256;
    wr0 = wn0; wr1 = wn1; wr2 = wn2; wr3 = wn3;
  }
  { // d = 124
    #pragma unroll
    for (int q = 0; q < 8; ++q) acc[q] = fma(xr[q], wr0, acc[q]);
  }

  // score[pt] = sum_j relu(h[pt][j]) * W2[j]  -> cross-lane f64 reduce
  double w2l = W2D[lane];
  double s[8];
  #pragma unroll
  for (int q = 0; q < 8; ++q) s[q] = fmax(acc[q], 0.0) * w2l;
  #pragma unroll
  for (int off = 32; off > 0; off >>= 1) {
    #pragma unroll
    for (int q = 0; q < 8; ++q) s[q] += __shfl_down(s[q], off);
  }
  if (lane == 0) {
    #pragma unroll
    for (int q = 0; q < 8; ++q) red[wv * 8 + q] = s[q];
  }
  __syncthreads();
  if (tid < K1_PTS) {
    double sc = red[tid] + b2D[0];
    double sg = 1.0 / (1.0 + exp(-sc));
    salD[p0 + tid] = sg;                     // f64 sort key (monotone == y*)
    salF[p0 + tid] = (float)sg;
  }
}

// ---- k2: per-batch softmax(sal/0.5) + cumsum(sal)/N, fp32, shfl-based ----
__global__ __launch_bounds__(256) void k2_softmax_cumsum(
    const float* __restrict__ salF, float* __restrict__ ystar,
    float* __restrict__ csal)
{
  __shared__ float wmax[4], wsum[4], wtot[4];
  int b = blockIdx.x, t = threadIdx.x, lane = t & 63, wv = t >> 6;
  const float4* s4 = (const float4*)(salF + (size_t)b * N_);
  float v[16];
  #pragma unroll
  for (int k = 0; k < 4; ++k) {
    float4 a = s4[t * 4 + k];
    v[4*k] = a.x; v[4*k+1] = a.y; v[4*k+2] = a.z; v[4*k+3] = a.w;
  }
  float m = v[0];
  #pragma unroll
  for (int i = 1; i < 16; ++i) m = fmaxf(m, v[i]);
  #pragma unroll
  for (int off = 32; off > 0; off >>= 1) m = fmaxf(m, __shfl_down(m, off));
  if (lane == 0) wmax[wv] = m;
  __syncthreads();
  float M = fmaxf(fmaxf(wmax[0], wmax[1]), fmaxf(wmax[2], wmax[3]));

  float e[16];
  float se = 0.f;
  #pragma unroll
  for (int i = 0; i < 16; ++i) { e[i] = expf((v[i] - M) * 2.0f); se += e[i]; }
  float ss = se;
  #pragma unroll
  for (int off = 32; off > 0; off >>= 1) ss += __shfl_down(ss, off);
  if (lane == 0) wsum[wv] = ss;
  __syncthreads();
  float denom = (wsum[0] + wsum[1]) + (wsum[2] + wsum[3]);
  float rdenom = 1.f / denom;

  float p[16];
  p[0] = v[0];
  #pragma unroll
  for (int i = 1; i < 16; ++i) p[i] = p[i-1] + v[i];
  float T = p[15];
  float incl = T;
  #pragma unroll
  for (int off = 1; off < 64; off <<= 1) {
    float nv = __shfl_up(incl, off);
    if (lane >= off) incl += nv;
  }
  float wexcl = incl - T;
  if (lane == 63) wtot[wv] = incl;
  __syncthreads();
  float woff = 0.f;
  for (int w = 0; w < 4; ++w) if (w < wv) woff += wtot[w];
  float base = woff + wexcl;

  float4* y4 = (float4*)(ystar + (size_t)b * N_);
  float4* c4 = (float4*)(csal + (size_t)b * N_);
  const float invN = 1.f / (float)N_;
  #pragma unroll
  for (int k = 0; k < 4; ++k) {
    float4 yo, co;
    yo.x = e[4*k]   * rdenom; co.x = (base + p[4*k])   * invN;
    yo.y = e[4*k+1] * rdenom; co.y = (base + p[4*k+1]) * invN;
    yo.z = e[4*k+2] * rdenom; co.z = (base + p[4*k+2]) * invN;
    yo.w = e[4*k+3] * rdenom; co.w = (base + p[4*k+3]) * invN;
    y4[t * 4 + k] = yo;
    c4[t * 4 + k] = co;
  }
}

// ---- k3a: sort 512-elem chunks desc on salD bits, keep top-256 ----
__global__ __launch_bounds__(256) void k3a_sortchunks(
    const double* __restrict__ salD, unsigned long long* __restrict__ candK,
    int* __restrict__ candI)
{
  __shared__ unsigned long long K[512];
  __shared__ int I[512];
  int bid = blockIdx.x, t = threadIdx.x;
  int b = bid >> 3, c = bid & 7;
  const double* y = salD + (size_t)b * N_ + c * 512;
  for (int i = t; i < 512; i += 256) {
    K[i] = __double_as_longlong(y[i]);      // y in (0,1): bits monotone
    I[i] = c * 512 + i;
  }
  __syncthreads();
  for (int k = 2; k <= 512; k <<= 1) {
    for (int j = k >> 1; j > 0; j >>= 1) {
      for (int i = t; i < 512; i += 256) {
        int l = i ^ j;
        if (l > i) {
          unsigned long long a = K[i], cc = K[l];
          int ai = I[i], ci = I[l];
          bool prec = (a > cc) || (a == cc && ai < ci);
          bool up = ((i & k) == 0);
          if (up ? !prec : prec) { K[i] = cc; K[l] = a; I[i] = ci; I[l] = ai; }
        }
      }
      __syncthreads();
    }
  }
  if (t < 256) {
    candK[(b * 8 + c) * 256 + t] = K[t];
    candI[(b * 8 + c) * 256 + t] = I[t];
  }
}

// ---- k3b: merge 8 sorted top-256 lists -> global sorted top-256 ----
__global__ __launch_bounds__(256) void k3b_merge(
    const unsigned long long* __restrict__ candK, const int* __restrict__ candI,
    int* __restrict__ topidx)
{
  __shared__ unsigned long long K[2048];
  __shared__ int I[2048];
  int b = blockIdx.x, t = threadIdx.x;
  for (int i = t; i < 2048; i += 256) {
    int r = i >> 9, o = i & 511;
    int lst = (o < 256) ? 2 * r : 2 * r + 1;
    int pos = (o < 256) ? o : 511 - o;
    K[i] = candK[(b * 8 + lst) * 256 + pos];
    I[i] = candI[(b * 8 + lst) * 256 + pos];
  }
  __syncthreads();

  #define CMPSWAP(i, l) { \
    unsigned long long a = K[i], cc = K[l]; \
    int ai = I[i], ci = I[l]; \
    bool prec = (a > cc) || (a == cc && ai < ci); \
    if (!prec) { K[i] = cc; K[l] = a; I[i] = ci; I[l] = ai; } }

  for (int j = 256; j > 0; j >>= 1) {
    for (int i = t; i < 2048; i += 256) {
      int l = i ^ j;
      if (l > i) CMPSWAP(i, l);
    }
    __syncthreads();
  }
  for (int i = t; i < 512; i += 256) {
    int pr = i >> 8, o = i & 255;
    int dst = pr * 1024 + 256 + o, src = pr * 1024 + 512 + 255 - o;
    K[dst] = K[src]; I[dst] = I[src];
  }
  __syncthreads();
  for (int j = 256; j > 0; j >>= 1) {
    for (int ii = t; ii < 1024; ii += 256) {
      int i = (ii < 512) ? ii : (ii + 512);
      int l = i ^ j;
      if (l > i) CMPSWAP(i, l);
    }
    __syncthreads();
  }
  for (int i = t; i < 256; i += 256) {
    K[256 + i] = K[1024 + 255 - i]; I[256 + i] = I[1024 + 255 - i];
  }
  __syncthreads();
  for (int j = 256; j > 0; j >>= 1) {
    for (int i = t; i < 512; i += 256) {
      int l = i ^ j;
      if (l > i) CMPSWAP(i, l);
    }
    __syncthreads();
  }
  if (t < 256) topidx[b * KEFF + t] = I[t];
  #undef CMPSWAP
}

// ---- k4a: gather top-32/block, dense->normalize->lift -> cloud[8192][64] ----
__global__ __launch_bounds__(256) void k4a_lift(
    const float* __restrict__ x, const float* __restrict__ sal,
    const float* __restrict__ csal, const int* __restrict__ topidx,
    const float* __restrict__ lift_W, const float* __restrict__ lift_b,
    const float* __restrict__ mu, const float* __restrict__ sigma,
    float* __restrict__ cloud)
{
  __shared__ float sd[32][ADIM];      // 16KB
  __shared__ float sW[ADIM * KDIM];   // 32KB
  __shared__ float snf[32];
  __shared__ int sidx[32];

  int t = threadIdx.x, bid = blockIdx.x;
  int b = bid >> 3, p0 = (bid & 7) * 32;

  if (t < 32) sidx[t] = topidx[b * KEFF + p0 + t];
  for (int e = t; e < ADIM * KDIM; e += 256) sW[e] = lift_W[e];
  __syncthreads();

  for (int e = t; e < 32 * ADIM; e += 256) {
    int p = e >> 7, a = e & 127;
    int n = sidx[p];
    int base = b * N_ + n;
    float v;
    if (a < IN_DIM)          v = x[(size_t)base * IN_DIM + a];
    else if (a == IN_DIM)    v = sal[base];
    else if (a == IN_DIM+1)  v = (float)n / (float)(N_ - 1);
    else                     v = csal[base];
    sd[p][a] = v;
  }
  __syncthreads();

  { // norms: 8 lanes per point (8-aligned groups within wave)
    int p = t >> 3, l8 = t & 7;
    float ss = 0.f;
    for (int a = l8; a < ADIM; a += 8) { float v = sd[p][a]; ss = fmaf(v, v, ss); }
    ss += __shfl_down(ss, 4);
    ss += __shfl_down(ss, 2);
    ss += __shfl_down(ss, 1);
    if (l8 == 0) snf[p] = 1.f / (sqrtf(ss) + EPS_);
  }
  __syncthreads();

  for (int e = t; e < 32 * ADIM; e += 256) {
    int p = e >> 7, a = e & 127;
    sd[p][a] = (sd[p][a] * snf[p] - mu[a]) / sigma[a];
  }
  __syncthreads();

  // lift: wave wv owns 8 points; lane = output dim k
  int wv = t >> 6, lane = t & 63;
  float acc[8];
  float lb = lift_b[lane];
  #pragma unroll
  for (int q = 0; q < 8; ++q) acc[q] = lb;
  #pragma unroll 1
  for (int a = 0; a < ADIM; a += 4) {
    float wl0 = sW[a*KDIM+lane],     wl1 = sW[(a+1)*KDIM+lane];
    float wl2 = sW[(a+2)*KDIM+lane], wl3 = sW[(a+3)*KDIM+lane];
    #pragma unroll
    for (int q = 0; q < 8; ++q) {
      int p = wv * 8 + q;
      acc[q] = fmaf(sd[p][a],   wl0, acc[q]);
      acc[q] = fmaf(sd[p][a+1], wl1, acc[q]);
      acc[q] = fmaf(sd[p][a+2], wl2, acc[q]);
      acc[q] = fmaf(sd[p][a+3], wl3, acc[q]);
    }
  }
  #pragma unroll
  for (int q = 0; q < 8; ++q) {
    int gp = b * KEFF + p0 + wv * 8 + q;
    cloud[(size_t)gp * KDIM + lane] = acc[q];    // coalesced 64 dwords
  }
}

// ---- k4b: proj GEMM. Block = 32 points x 256 cols; 1024 blocks. ----
// cloud tile in LDS (broadcast reads), proj_W rows double-buffered in regs.
__global__ __launch_bounds__(256) void k4b_proj(
    const float* __restrict__ cloud, const float* __restrict__ proj_W,
    const float* __restrict__ proj_b, float* __restrict__ tokens)
{
  __shared__ float sc[32][KDIM];      // 8KB
  int t = threadIdx.x;
  int pg = blockIdx.x >> 2, cg = blockIdx.x & 3;

  { // load cloud tile: 2048 floats = 512 float4
    const float4* src = (const float4*)(cloud + (size_t)pg * 32 * KDIM);
    float4* dst = (float4*)sc;
    dst[t] = src[t];
    dst[t + 256] = src[t + 256];
  }
  __syncthreads();

  int col = cg * 256 + t;
  float acc[32];
  #pragma unroll
  for (int p = 0; p < 32; ++p) acc[p] = 0.f;

  float4 wcur;
  wcur.x = proj_W[0*DMODEL + col]; wcur.y = proj_W[1*DMODEL + col];
  wcur.z = proj_W[2*DMODEL + col]; wcur.w = proj_W[3*DMODEL + col];
  #pragma unroll 1
  for (int c = 0; c < KDIM; c += 4) {
    float4 wnext = {0.f, 0.f, 0.f, 0.f};
    if (c + 4 < KDIM) {
      wnext.x = proj_W[(size_t)(c+4)*DMODEL + col];
      wnext.y = proj_W[(size_t)(c+5)*DMODEL + col];
      wnext.z = proj_W[(size_t)(c+6)*DMODEL + col];
      wnext.w = proj_W[(size_t)(c+7)*DMODEL + col];
    }
    #pragma unroll
    for (int p = 0; p < 32; ++p) {
      float4 cv = *(const float4*)&sc[p][c];     // broadcast b128
      acc[p] = fmaf(cv.x, wcur.x, acc[p]);
      acc[p] = fmaf(cv.y, wcur.y, acc[p]);
      acc[p] = fmaf(cv.z, wcur.z, acc[p]);
      acc[p] = fmaf(cv.w, wcur.w, acc[p]);
    }
    wcur = wnext;
  }

  float pb = proj_b[col];
  int gp0 = pg * 32;
  #pragma unroll
  for (int p = 0; p < 32; ++p)
    tokens[(size_t)(gp0 + p) * DMODEL + col] = acc[p] + pb;
}

extern "C" void kernel_launch(void* const* d_in, const int* in_sizes, int n_in,
                              void* d_out, int out_size, void* d_ws, size_t ws_size,
                              hipStream_t stream)
{
  const float* x      = (const float*)d_in[0];
  const float* W1     = (const float*)d_in[1];
  const float* b1     = (const float*)d_in[2];
  const float* W2     = (const float*)d_in[3];
  const float* b2     = (const float*)d_in[4];
  const float* lift_W = (const float*)d_in[5];
  const float* lift_b = (const float*)d_in[6];
  const float* mu     = (const float*)d_in[7];
  const float* sigma  = (const float*)d_in[8];
  const float* proj_W = (const float*)d_in[9];
  const float* proj_b = (const float*)d_in[10];

  float* tokens = (float*)d_out;                        // [B,256,1024]
  float* ystarF = tokens + (size_t)B_ * KEFF * DMODEL;  // [B,N]

  // workspace layout with overlay:
  //   [0, 2MB): salD(1MB) | candK(512K) | candI(256K)   -- all dead after k3b
  //             cloud(2MB) overlays this region (written by k4a)
  //   [2MB, ...): W1D/b1D/W2D/b2D (~65KB) | salF(512K) | csalF(512K) | topidx(32K)
  char* wsb = (char*)d_ws;
  double* salD   = (double*)wsb;                                   // B*N f64
  unsigned long long* candK = (unsigned long long*)(wsb + (1<<20));
  int*    candI  = (int*)(wsb + (1<<20) + (512<<10));
  float*  cloud  = (float*)wsb;                                    // overlay
  double* W1D    = (double*)(wsb + (2<<20));
  double* b1D    = W1D + IN_DIM * HID;
  double* W2D    = b1D + HID;
  double* b2D    = W2D + HID;
  float*  salF   = (float*)(wsb + (2<<20) + 65536);
  float*  csalF  = salF + (size_t)B_ * N_;
  int*    topidx = (int*)(csalF + (size_t)B_ * N_);

  k0_cvt<<<(IN_DIM * HID + 255) / 256, 256, 0, stream>>>(
      W1, b1, W2, b2, W1D, b1D, W2D, b2D);
  k1_saliency<<<(B_ * N_) / K1_PTS, 512, 0, stream>>>(
      x, W1D, b1D, W2D, b2D, salD, salF);
  k2_softmax_cumsum<<<B_, 256, 0, stream>>>(salF, ystarF, csalF);
  k3a_sortchunks<<<B_ * 8, 256, 0, stream>>>(salD, candK, candI);
  k3b_merge<<<B_, 256, 0, stream>>>(candK, candI, topidx);
  k4a_lift<<<B_ * 8, 256, 0, stream>>>(
      x, salF, csalF, topidx, lift_W, lift_b, mu, sigma, cloud);
  k4b_proj<<<(B_ * KEFF / 32) * (DMODEL / 256), 256, 0, stream>>>(
      cloud, proj_W, proj_b, tokens);
}

// Round 3
// 323.506 us; speedup vs baseline: 1.0604x; 1.0604x over previous
//
#include <hip/hip_runtime.h>
#include <cmath>

#define B_ 32
#define N_ 4096
#define IN_DIM 125
#define ADIM 128
#define KDIM 64
#define DMODEL 1024
#define HID 64
#define KEFF 256
#define EPS_ 1e-6f

// ---------- k0: convert MLP weights to f64 (once per launch) ----------
__global__ __launch_bounds__(256) void k0_cvt(
    const float* __restrict__ W1, const float* __restrict__ b1,
    const float* __restrict__ W2, const float* __restrict__ b2,
    double* __restrict__ W1D, double* __restrict__ b1D,
    double* __restrict__ W2D, double* __restrict__ b2D)
{
  int t = blockIdx.x * 256 + threadIdx.x;
  if (t < IN_DIM * HID) W1D[t] = (double)W1[t];
  if (t < HID) { b1D[t] = (double)b1[t]; W2D[t] = (double)W2[t]; }
  if (t == 0) b2D[0] = (double)b2[0];
}

// ---------- k1: saliency MLP in fp64, v4 ----------
// Unified theory of r0/r1/r2 stalls: W via s_load is doomed (SMEM returns
// OOO among themselves -> consuming any s_load forces lgkmcnt(0), draining
// the prefetch -> per-iter serial K$/L2 latency, occupancy-invariant ->
// VALUBusy pinned 52%). r2's uniform-x-from-LDS was LDS-pipe-bound (22%).
// v4 = r0 skeleton (lane=point, wave=j-octet, x per-lane from LDS) with:
//  - W via per-lane VMEM, address derived from threadIdx (divergent-typed
//    so LLVM can't scalarize back to s_load) -> vmcnt-counted, in-order,
//    2-row-deep register pipeline actually works.
//  - 2 pts/lane (W-issue amortized to ~25% of FMA issue).
//  - x reads as float4 from XOR-swizzled LDS (conflict-free, 1 lgkm / 4d).
// FMA order over d unchanged -> bit-identical salD to passing rounds.
#define K1_PTS 128
__global__ __launch_bounds__(512, 4) void k1_saliency(
    const float* __restrict__ x, const double* __restrict__ W1D,
    const double* __restrict__ b1D, const double* __restrict__ W2D,
    const double* __restrict__ b2D, double* __restrict__ salD,
    float* __restrict__ salF)
{
  __shared__ float xs[K1_PTS * 128];   // 65536 B; 16B-slot XOR swizzle
  int tid = threadIdx.x;
  int p0 = blockIdx.x * K1_PTS;

  // dword index of x[p][d] in xs: row stride 128, slot s=d>>2 stored at s^(p&7)
#define XIDX(p, d) (((p) << 7) + (((((d) >> 2) ^ ((p) & 7))) << 2) + ((d) & 3))

  { // stage: coalesced global b32 reads, swizzled ds_write_b32
    const float* xg = x + (size_t)p0 * IN_DIM;
    for (int e = tid; e < K1_PTS * IN_DIM; e += 512) {
      int p = e / IN_DIM, d = e - p * IN_DIM;
      xs[XIDX(p, d)] = xg[e];
    }
  }
  __syncthreads();

  int wv = tid >> 6;
  int lane = tid & 63;
  int jb = (tid >> 6) << 3;   // divergent-typed on purpose (keep W in VMEM)

  double acc0[8], acc1[8];
  #pragma unroll
  for (int jj = 0; jj < 8; ++jj) {
    double bv = b1D[jb + jj];
    acc0[jj] = bv; acc1[jj] = bv;
  }

  const double* wbase = W1D + jb;
  // W pipeline: wA = rows {d,d+1}, wB = rows {d+2,d+3}; 16 doubles each
  double wA[16], wB[16];
  #pragma unroll
  for (int c = 0; c < 4; ++c) {
    *(double2*)&wA[2*c]     = *(const double2*)(wbase + 0*64 + 2*c);
    *(double2*)&wA[8+2*c]   = *(const double2*)(wbase + 1*64 + 2*c);
    *(double2*)&wB[2*c]     = *(const double2*)(wbase + 2*64 + 2*c);
    *(double2*)&wB[8+2*c]   = *(const double2*)(wbase + 3*64 + 2*c);
  }

  #pragma unroll 1
  for (int d = 0; d < 120; d += 4) {
    float4 xa = *(const float4*)&xs[XIDX(lane,      d)];
    float4 xb = *(const float4*)&xs[XIDX(lane + 64, d)];
    // rows d, d+1 from wA
    {
      double t0 = (double)xa.x, u0 = (double)xb.x;
      #pragma unroll
      for (int jj = 0; jj < 8; ++jj) {
        acc0[jj] = fma(t0, wA[jj], acc0[jj]);
        acc1[jj] = fma(u0, wA[jj], acc1[jj]);
      }
      double t1 = (double)xa.y, u1 = (double)xb.y;
      #pragma unroll
      for (int jj = 0; jj < 8; ++jj) {
        acc0[jj] = fma(t1, wA[8+jj], acc0[jj]);
        acc1[jj] = fma(u1, wA[8+jj], acc1[jj]);
      }
    }
    // prefetch rows d+4, d+5 into wA (vmcnt-covered by the wB compute below)
    #pragma unroll
    for (int c = 0; c < 4; ++c) {
      *(double2*)&wA[2*c]   = *(const double2*)(wbase + (size_t)(d+4)*64 + 2*c);
      *(double2*)&wA[8+2*c] = *(const double2*)(wbase + (size_t)(d+5)*64 + 2*c);
    }
    // rows d+2, d+3 from wB
    {
      double t2 = (double)xa.z, u2 = (double)xb.z;
      #pragma unroll
      for (int jj = 0; jj < 8; ++jj) {
        acc0[jj] = fma(t2, wB[jj], acc0[jj]);
        acc1[jj] = fma(u2, wB[jj], acc1[jj]);
      }
      double t3 = (double)xa.w, u3 = (double)xb.w;
      #pragma unroll
      for (int jj = 0; jj < 8; ++jj) {
        acc0[jj] = fma(t3, wB[8+jj], acc0[jj]);
        acc1[jj] = fma(u3, wB[8+jj], acc1[jj]);
      }
    }
    // prefetch rows d+6, d+7 into wB
    #pragma unroll
    for (int c = 0; c < 4; ++c) {
      *(double2*)&wB[2*c]   = *(const double2*)(wbase + (size_t)(d+6)*64 + 2*c);
      *(double2*)&wB[8+2*c] = *(const double2*)(wbase + (size_t)(d+7)*64 + 2*c);
    }
  }

  { // d = 120..123: wA holds rows 120,121; wB holds 122,123
    float4 xa = *(const float4*)&xs[XIDX(lane,      120)];
    float4 xb = *(const float4*)&xs[XIDX(lane + 64, 120)];
    double t0 = (double)xa.x, u0 = (double)xb.x;
    #pragma unroll
    for (int jj = 0; jj < 8; ++jj) {
      acc0[jj] = fma(t0, wA[jj], acc0[jj]);
      acc1[jj] = fma(u0, wA[jj], acc1[jj]);
    }
    double t1 = (double)xa.y, u1 = (double)xb.y;
    #pragma unroll
    for (int jj = 0; jj < 8; ++jj) {
      acc0[jj] = fma(t1, wA[8+jj], acc0[jj]);
      acc1[jj] = fma(u1, wA[8+jj], acc1[jj]);
    }
    // row 124 into wA[0..7]
    #pragma unroll
    for (int c = 0; c < 4; ++c)
      *(double2*)&wA[2*c] = *(const double2*)(wbase + (size_t)124*64 + 2*c);
    double t2 = (double)xa.z, u2 = (double)xb.z;
    #pragma unroll
    for (int jj = 0; jj < 8; ++jj) {
      acc0[jj] = fma(t2, wB[jj], acc0[jj]);
      acc1[jj] = fma(u2, wB[jj], acc1[jj]);
    }
    double t3 = (double)xa.w, u3 = (double)xb.w;
    #pragma unroll
    for (int jj = 0; jj < 8; ++jj) {
      acc0[jj] = fma(t3, wB[8+jj], acc0[jj]);
      acc1[jj] = fma(u3, wB[8+jj], acc1[jj]);
    }
  }

  { // d = 124
    double t = (double)xs[XIDX(lane, 124)];
    double u = (double)xs[XIDX(lane + 64, 124)];
    #pragma unroll
    for (int jj = 0; jj < 8; ++jj) {
      acc0[jj] = fma(t, wA[jj], acc0[jj]);
      acc1[jj] = fma(u, wA[jj], acc1[jj]);
    }
  }

  // score parts: sum_j relu(h)*W2[j] over this wave's octet
  double w2v[8];
  #pragma unroll
  for (int c = 0; c < 4; ++c)
    *(double2*)&w2v[2*c] = *(const double2*)(W2D + jb + 2*c);
  double part0 = 0.0, part1 = 0.0;
  #pragma unroll
  for (int jj = 0; jj < 8; ++jj) {
    part0 = fma(fmax(acc0[jj], 0.0), w2v[jj], part0);
    part1 = fma(fmax(acc1[jj], 0.0), w2v[jj], part1);
  }
  __syncthreads();                           // xs reads done
  double* red = (double*)xs;                 // [8][128] overlay (8KB)
  red[wv * K1_PTS + lane] = part0;
  red[wv * K1_PTS + 64 + lane] = part1;
  __syncthreads();
  if (tid < K1_PTS) {
    double s = b2D[0];
    #pragma unroll
    for (int w = 0; w < 8; ++w) s += red[w * K1_PTS + tid];
    double sg = 1.0 / (1.0 + exp(-s));
    salD[p0 + tid] = sg;                     // f64 sort key (monotone == y*)
    salF[p0 + tid] = (float)sg;
  }
#undef XIDX
}

// ---- k2: per-batch softmax(sal/0.5) + cumsum(sal)/N, fp32, shfl-based ----
__global__ __launch_bounds__(256) void k2_softmax_cumsum(
    const float* __restrict__ salF, float* __restrict__ ystar,
    float* __restrict__ csal)
{
  __shared__ float wmax[4], wsum[4], wtot[4];
  int b = blockIdx.x, t = threadIdx.x, lane = t & 63, wv = t >> 6;
  const float4* s4 = (const float4*)(salF + (size_t)b * N_);
  float v[16];
  #pragma unroll
  for (int k = 0; k < 4; ++k) {
    float4 a = s4[t * 4 + k];
    v[4*k] = a.x; v[4*k+1] = a.y; v[4*k+2] = a.z; v[4*k+3] = a.w;
  }
  float m = v[0];
  #pragma unroll
  for (int i = 1; i < 16; ++i) m = fmaxf(m, v[i]);
  #pragma unroll
  for (int off = 32; off > 0; off >>= 1) m = fmaxf(m, __shfl_down(m, off));
  if (lane == 0) wmax[wv] = m;
  __syncthreads();
  float M = fmaxf(fmaxf(wmax[0], wmax[1]), fmaxf(wmax[2], wmax[3]));

  float e[16];
  float se = 0.f;
  #pragma unroll
  for (int i = 0; i < 16; ++i) { e[i] = expf((v[i] - M) * 2.0f); se += e[i]; }
  float ss = se;
  #pragma unroll
  for (int off = 32; off > 0; off >>= 1) ss += __shfl_down(ss, off);
  if (lane == 0) wsum[wv] = ss;
  __syncthreads();
  float denom = (wsum[0] + wsum[1]) + (wsum[2] + wsum[3]);
  float rdenom = 1.f / denom;

  float p[16];
  p[0] = v[0];
  #pragma unroll
  for (int i = 1; i < 16; ++i) p[i] = p[i-1] + v[i];
  float T = p[15];
  float incl = T;
  #pragma unroll
  for (int off = 1; off < 64; off <<= 1) {
    float nv = __shfl_up(incl, off);
    if (lane >= off) incl += nv;
  }
  float wexcl = incl - T;
  if (lane == 63) wtot[wv] = incl;
  __syncthreads();
  float woff = 0.f;
  for (int w = 0; w < 4; ++w) if (w < wv) woff += wtot[w];
  float base = woff + wexcl;

  float4* y4 = (float4*)(ystar + (size_t)b * N_);
  float4* c4 = (float4*)(csal + (size_t)b * N_);
  const float invN = 1.f / (float)N_;
  #pragma unroll
  for (int k = 0; k < 4; ++k) {
    float4 yo, co;
    yo.x = e[4*k]   * rdenom; co.x = (base + p[4*k])   * invN;
    yo.y = e[4*k+1] * rdenom; co.y = (base + p[4*k+1]) * invN;
    yo.z = e[4*k+2] * rdenom; co.z = (base + p[4*k+2]) * invN;
    yo.w = e[4*k+3] * rdenom; co.w = (base + p[4*k+3]) * invN;
    y4[t * 4 + k] = yo;
    c4[t * 4 + k] = co;
  }
}

// ---- k3a: sort 512-elem chunks desc on salD bits, keep top-256 ----
__global__ __launch_bounds__(256) void k3a_sortchunks(
    const double* __restrict__ salD, unsigned long long* __restrict__ candK,
    int* __restrict__ candI)
{
  __shared__ unsigned long long K[512];
  __shared__ int I[512];
  int bid = blockIdx.x, t = threadIdx.x;
  int b = bid >> 3, c = bid & 7;
  const double* y = salD + (size_t)b * N_ + c * 512;
  for (int i = t; i < 512; i += 256) {
    K[i] = __double_as_longlong(y[i]);      // y in (0,1): bits monotone
    I[i] = c * 512 + i;
  }
  __syncthreads();
  for (int k = 2; k <= 512; k <<= 1) {
    for (int j = k >> 1; j > 0; j >>= 1) {
      for (int i = t; i < 512; i += 256) {
        int l = i ^ j;
        if (l > i) {
          unsigned long long a = K[i], cc = K[l];
          int ai = I[i], ci = I[l];
          bool prec = (a > cc) || (a == cc && ai < ci);
          bool up = ((i & k) == 0);
          if (up ? !prec : prec) { K[i] = cc; K[l] = a; I[i] = ci; I[l] = ai; }
        }
      }
      __syncthreads();
    }
  }
  if (t < 256) {
    candK[(b * 8 + c) * 256 + t] = K[t];
    candI[(b * 8 + c) * 256 + t] = I[t];
  }
}

// ---- k3b: merge 8 sorted top-256 lists -> global sorted top-256 ----
__global__ __launch_bounds__(256) void k3b_merge(
    const unsigned long long* __restrict__ candK, const int* __restrict__ candI,
    int* __restrict__ topidx)
{
  __shared__ unsigned long long K[2048];
  __shared__ int I[2048];
  int b = blockIdx.x, t = threadIdx.x;
  for (int i = t; i < 2048; i += 256) {
    int r = i >> 9, o = i & 511;
    int lst = (o < 256) ? 2 * r : 2 * r + 1;
    int pos = (o < 256) ? o : 511 - o;
    K[i] = candK[(b * 8 + lst) * 256 + pos];
    I[i] = candI[(b * 8 + lst) * 256 + pos];
  }
  __syncthreads();

  #define CMPSWAP(i, l) { \
    unsigned long long a = K[i], cc = K[l]; \
    int ai = I[i], ci = I[l]; \
    bool prec = (a > cc) || (a == cc && ai < ci); \
    if (!prec) { K[i] = cc; K[l] = a; I[i] = ci; I[l] = ai; } }

  for (int j = 256; j > 0; j >>= 1) {
    for (int i = t; i < 2048; i += 256) {
      int l = i ^ j;
      if (l > i) CMPSWAP(i, l);
    }
    __syncthreads();
  }
  for (int i = t; i < 512; i += 256) {
    int pr = i >> 8, o = i & 255;
    int dst = pr * 1024 + 256 + o, src = pr * 1024 + 512 + 255 - o;
    K[dst] = K[src]; I[dst] = I[src];
  }
  __syncthreads();
  for (int j = 256; j > 0; j >>= 1) {
    for (int ii = t; ii < 1024; ii += 256) {
      int i = (ii < 512) ? ii : (ii + 512);
      int l = i ^ j;
      if (l > i) CMPSWAP(i, l);
    }
    __syncthreads();
  }
  for (int i = t; i < 256; i += 256) {
    K[256 + i] = K[1024 + 255 - i]; I[256 + i] = I[1024 + 255 - i];
  }
  __syncthreads();
  for (int j = 256; j > 0; j >>= 1) {
    for (int i = t; i < 512; i += 256) {
      int l = i ^ j;
      if (l > i) CMPSWAP(i, l);
    }
    __syncthreads();
  }
  if (t < 256) topidx[b * KEFF + t] = I[t];
  #undef CMPSWAP
}

// ---- k4a: gather top-32/block, dense->normalize->lift -> cloud[8192][64] ----
__global__ __launch_bounds__(256) void k4a_lift(
    const float* __restrict__ x, const float* __restrict__ sal,
    const float* __restrict__ csal, const int* __restrict__ topidx,
    const float* __restrict__ lift_W, const float* __restrict__ lift_b,
    const float* __restrict__ mu, const float* __restrict__ sigma,
    float* __restrict__ cloud)
{
  __shared__ float sd[32][ADIM];      // 16KB
  __shared__ float sW[ADIM * KDIM];   // 32KB
  __shared__ float snf[32];
  __shared__ int sidx[32];

  int t = threadIdx.x, bid = blockIdx.x;
  int b = bid >> 3, p0 = (bid & 7) * 32;

  if (t < 32) sidx[t] = topidx[b * KEFF + p0 + t];
  for (int e = t; e < ADIM * KDIM; e += 256) sW[e] = lift_W[e];
  __syncthreads();

  for (int e = t; e < 32 * ADIM; e += 256) {
    int p = e >> 7, a = e & 127;
    int n = sidx[p];
    int base = b * N_ + n;
    float v;
    if (a < IN_DIM)          v = x[(size_t)base * IN_DIM + a];
    else if (a == IN_DIM)    v = sal[base];
    else if (a == IN_DIM+1)  v = (float)n / (float)(N_ - 1);
    else                     v = csal[base];
    sd[p][a] = v;
  }
  __syncthreads();

  { // norms: 8 lanes per point (8-aligned groups within wave)
    int p = t >> 3, l8 = t & 7;
    float ss = 0.f;
    for (int a = l8; a < ADIM; a += 8) { float v = sd[p][a]; ss = fmaf(v, v, ss); }
    ss += __shfl_down(ss, 4);
    ss += __shfl_down(ss, 2);
    ss += __shfl_down(ss, 1);
    if (l8 == 0) snf[p] = 1.f / (sqrtf(ss) + EPS_);
  }
  __syncthreads();

  for (int e = t; e < 32 * ADIM; e += 256) {
    int p = e >> 7, a = e & 127;
    sd[p][a] = (sd[p][a] * snf[p] - mu[a]) / sigma[a];
  }
  __syncthreads();

  // lift: wave wv owns 8 points; lane = output dim k
  int wv = t >> 6, lane = t & 63;
  float acc[8];
  float lb = lift_b[lane];
  #pragma unroll
  for (int q = 0; q < 8; ++q) acc[q] = lb;
  #pragma unroll 1
  for (int a = 0; a < ADIM; a += 4) {
    float wl0 = sW[a*KDIM+lane],     wl1 = sW[(a+1)*KDIM+lane];
    float wl2 = sW[(a+2)*KDIM+lane], wl3 = sW[(a+3)*KDIM+lane];
    #pragma unroll
    for (int q = 0; q < 8; ++q) {
      int p = wv * 8 + q;
      acc[q] = fmaf(sd[p][a],   wl0, acc[q]);
      acc[q] = fmaf(sd[p][a+1], wl1, acc[q]);
      acc[q] = fmaf(sd[p][a+2], wl2, acc[q]);
      acc[q] = fmaf(sd[p][a+3], wl3, acc[q]);
    }
  }
  #pragma unroll
  for (int q = 0; q < 8; ++q) {
    int gp = b * KEFF + p0 + wv * 8 + q;
    cloud[(size_t)gp * KDIM + lane] = acc[q];    // coalesced 64 dwords
  }
}

// ---- k4b: proj GEMM. Block = 32 points x 256 cols; 1024 blocks. ----
// cloud tile in LDS (broadcast reads), proj_W rows double-buffered in regs.
__global__ __launch_bounds__(256) void k4b_proj(
    const float* __restrict__ cloud, const float* __restrict__ proj_W,
    const float* __restrict__ proj_b, float* __restrict__ tokens)
{
  __shared__ float sc[32][KDIM];      // 8KB
  int t = threadIdx.x;
  int pg = blockIdx.x >> 2, cg = blockIdx.x & 3;

  { // load cloud tile: 2048 floats = 512 float4
    const float4* src = (const float4*)(cloud + (size_t)pg * 32 * KDIM);
    float4* dst = (float4*)sc;
    dst[t] = src[t];
    dst[t + 256] = src[t + 256];
  }
  __syncthreads();

  int col = cg * 256 + t;
  float acc[32];
  #pragma unroll
  for (int p = 0; p < 32; ++p) acc[p] = 0.f;

  float4 wcur;
  wcur.x = proj_W[0*DMODEL + col]; wcur.y = proj_W[1*DMODEL + col];
  wcur.z = proj_W[2*DMODEL + col]; wcur.w = proj_W[3*DMODEL + col];
  #pragma unroll 1
  for (int c = 0; c < KDIM; c += 4) {
    float4 wnext = {0.f, 0.f, 0.f, 0.f};
    if (c + 4 < KDIM) {
      wnext.x = proj_W[(size_t)(c+4)*DMODEL + col];
      wnext.y = proj_W[(size_t)(c+5)*DMODEL + col];
      wnext.z = proj_W[(size_t)(c+6)*DMODEL + col];
      wnext.w = proj_W[(size_t)(c+7)*DMODEL + col];
    }
    #pragma unroll
    for (int p = 0; p < 32; ++p) {
      float4 cv = *(const float4*)&sc[p][c];     // broadcast b128
      acc[p] = fmaf(cv.x, wcur.x, acc[p]);
      acc[p] = fmaf(cv.y, wcur.y, acc[p]);
      acc[p] = fmaf(cv.z, wcur.z, acc[p]);
      acc[p] = fmaf(cv.w, wcur.w, acc[p]);
    }
    wcur = wnext;
  }

  float pb = proj_b[col];
  int gp0 = pg * 32;
  #pragma unroll
  for (int p = 0; p < 32; ++p)
    tokens[(size_t)(gp0 + p) * DMODEL + col] = acc[p] + pb;
}

extern "C" void kernel_launch(void* const* d_in, const int* in_sizes, int n_in,
                              void* d_out, int out_size, void* d_ws, size_t ws_size,
                              hipStream_t stream)
{
  const float* x      = (const float*)d_in[0];
  const float* W1     = (const float*)d_in[1];
  const float* b1     = (const float*)d_in[2];
  const float* W2     = (const float*)d_in[3];
  const float* b2     = (const float*)d_in[4];
  const float* lift_W = (const float*)d_in[5];
  const float* lift_b = (const float*)d_in[6];
  const float* mu     = (const float*)d_in[7];
  const float* sigma  = (const float*)d_in[8];
  const float* proj_W = (const float*)d_in[9];
  const float* proj_b = (const float*)d_in[10];

  float* tokens = (float*)d_out;                        // [B,256,1024]
  float* ystarF = tokens + (size_t)B_ * KEFF * DMODEL;  // [B,N]

  // workspace layout with overlay:
  //   [0, 2MB): salD(1MB) | candK(512K) | candI(256K)   -- all dead after k3b
  //             cloud(2MB) overlays this region (written by k4a)
  //   [2MB, ...): W1D/b1D/W2D/b2D (~65KB) | salF(512K) | csalF(512K) | topidx(32K)
  char* wsb = (char*)d_ws;
  double* salD   = (double*)wsb;                                   // B*N f64
  unsigned long long* candK = (unsigned long long*)(wsb + (1<<20));
  int*    candI  = (int*)(wsb + (1<<20) + (512<<10));
  float*  cloud  = (float*)wsb;                                    // overlay
  double* W1D    = (double*)(wsb + (2<<20));
  double* b1D    = W1D + IN_DIM * HID;
  double* W2D    = b1D + HID;
  double* b2D    = W2D + HID;
  float*  salF   = (float*)(wsb + (2<<20) + 65536);
  float*  csalF  = salF + (size_t)B_ * N_;
  int*    topidx = (int*)(csalF + (size_t)B_ * N_);

  k0_cvt<<<(IN_DIM * HID + 255) / 256, 256, 0, stream>>>(
      W1, b1, W2, b2, W1D, b1D, W2D, b2D);
  k1_saliency<<<(B_ * N_) / K1_PTS, 512, 0, stream>>>(
      x, W1D, b1D, W2D, b2D, salD, salF);
  k2_softmax_cumsum<<<B_, 256, 0, stream>>>(salF, ystarF, csalF);
  k3a_sortchunks<<<B_ * 8, 256, 0, stream>>>(salD, candK, candI);
  k3b_merge<<<B_, 256, 0, stream>>>(candK, candI, topidx);
  k4a_lift<<<B_ * 8, 256, 0, stream>>>(
      x, salF, csalF, topidx, lift_W, lift_b, mu, sigma, cloud);
  k4b_proj<<<(B_ * KEFF / 32) * (DMODEL / 256), 256, 0, stream>>>(
      cloud, proj_W, proj_b, tokens);
}